// Round 5
// baseline (110.281 us; speedup 1.0000x reference)
//
#include <hip/hip_runtime.h>

// Sinkhorn top-k, sorted-value domain, x <- 1/(Mx), 200 apps.
// R21 = R18's exact per-app dataflow, but TWO batches per workgroup
// (512 threads = 8 waves; waves 0-3 -> batch 2b, waves 4-7 -> batch 2b+1,
// grid=8). Rationale (R16/R18/R20 post-mortem): all structures sit at
// ~480-1050 cyc/app while pure issue work is 80-150 cyc -> the binding term
// is lone-wave issue cadence + unhidden ds_read/rcp/dep latency when each
// SIMD hosts a single wave. Pairing two INDEPENDENT batches per SIMD hides
// each stream's latency under the other's issue slots at zero extra serial
// work. Per-batch dataflow (window values, 4-chain dot order, zero pads,
// per-app barrier) is bit-identical to R18 -> absmax stays 0.0078125.

#define N      512
#define BATCH  16
#define KTOP   50
#define NAPPS  200
#define NJ     11          // window dwords per row pair
#define COEF   1442.6950408889634f   // log2(e)/EPSILON, EPSILON=1e-3
#define ONEH2  0x3C003C00u
#define NT     512         // 8 waves = 2 batches x 4 waves
#define XPAD   5           // zero pad dwords at each end of x buffer
#define XLEN   (256 + 2 * XPAD)

typedef _Float16 h2 __attribute__((ext_vector_type(2)));

static __device__ __forceinline__ h2 pack2(float a, float b) {
    return __builtin_bit_cast(h2, __builtin_amdgcn_cvt_pkrtz(a, b));
}
static __device__ __forceinline__ h2 uh(unsigned v) {
    return __builtin_bit_cast(h2, v);
}

__global__
__attribute__((amdgpu_flat_work_group_size(NT, NT)))
void sinkhorn_topk_kernel(const float* __restrict__ scores,
                          float* __restrict__ out) {
    __shared__ __align__(16) float tv[2][N];
    __shared__ int                 ti[2][N];
    __shared__ unsigned            xb[2][2][XLEN]; // [batch-half][buf][dword]

    const int g = threadIdx.x;              // 0..511
    const int h = g >> 8;                   // batch half 0/1
    const int t = g & 255;                  // pair index within batch
    const int b = blockIdx.x * 2 + h;       // global batch id

    ((float2*)tv[h])[t] = ((const float2*)(scores + b * N))[t];
    ti[h][2 * t]     = 2 * t;
    ti[h][2 * t + 1] = 2 * t + 1;
    if (t < XPAD) {                         // zero pads (DPP 0-fill semantics)
        xb[h][0][t] = 0u;            xb[h][1][t] = 0u;
        xb[h][0][XLEN - 1 - t] = 0u; xb[h][1][XLEN - 1 - t] = 0u;
    }
    xb[h][0][XPAD + t] = ONEH2;             // x_0 = 1.0 pairs
    __syncthreads();

    // ---- bitonic sort, descending (256 pairs per batch, both halves) ----
    for (int k = 2; k <= N; k <<= 1) {
        for (int j = k >> 1; j > 0; j >>= 1) {
            int i = ((t & ~(j - 1)) << 1) | (t & (j - 1));
            int p = i | j;
            float va = tv[h][i], vb = tv[h][p];
            bool up = ((i & k) == 0);
            bool sw = up ? (va < vb) : (va > vb);
            if (sw) {
                tv[h][i] = vb; tv[h][p] = va;
                int t_ = ti[h][i]; ti[h][i] = ti[h][p]; ti[h][p] = t_;
            }
            __syncthreads();
        }
    }

    // ---- K band: both rows of the pair use window dwords 0..10 ----
    const int gb = 2 * t - 10;              // global half-index of window dword 0
    const float t0 = tv[h][2 * t], t1 = tv[h][2 * t + 1];
    h2 K2[2][NJ];                           // 22 dwords/lane
#pragma unroll
    for (int d = 0; d < NJ; ++d) {
        int g0 = gb + 2 * d, g1 = g0 + 1;
        int c0 = min(max(g0, 0), N - 1), c1 = min(max(g1, 0), N - 1);
        float s0 = tv[h][c0], s1 = tv[h][c1];
        float d00 = t0 - s0, d01 = t0 - s1;
        float d10 = t1 - s0, d11 = t1 - s1;
        K2[0][d] = pack2(exp2f(-COEF * d00 * d00), exp2f(-COEF * d01 * d01));
        K2[1][d] = pack2(exp2f(-COEF * d10 * d10), exp2f(-COEF * d11 * d11));
    }

    // ---- 200 apps: read window from rb, dot, rcp, store to wb, barrier ----
    unsigned w[NJ];
    unsigned x = ONEH2;

    auto run_app = [&](const unsigned* rb, unsigned* wb) {
#pragma unroll
        for (int d = 0; d < NJ; ++d) w[d] = rb[t + d];   // dwords t-5..t+5
        // 4 chains (even/odd split per row) for dep-latency cover
        float a0 = __builtin_amdgcn_fdot2(K2[0][0], uh(w[0]), 0.f, false);
        float a1 = __builtin_amdgcn_fdot2(K2[1][0], uh(w[0]), 0.f, false);
        float b0 = __builtin_amdgcn_fdot2(K2[0][1], uh(w[1]), 0.f, false);
        float b1 = __builtin_amdgcn_fdot2(K2[1][1], uh(w[1]), 0.f, false);
#pragma unroll
        for (int d = 2; d < NJ; d += 2) {
            a0 = __builtin_amdgcn_fdot2(K2[0][d], uh(w[d]), a0, false);
            a1 = __builtin_amdgcn_fdot2(K2[1][d], uh(w[d]), a1, false);
            if (d + 1 < NJ) {
                b0 = __builtin_amdgcn_fdot2(K2[0][d + 1], uh(w[d + 1]), b0, false);
                b1 = __builtin_amdgcn_fdot2(K2[1][d + 1], uh(w[d + 1]), b1, false);
            }
        }
        float s0 = a0 + b0, s1 = a1 + b1;
        x = __builtin_bit_cast(unsigned,
                pack2(__builtin_amdgcn_rcpf(s0), __builtin_amdgcn_rcpf(s1)));
        if (wb) {
            wb[XPAD + t] = x;
            __syncthreads();
        }
    };

    const unsigned* B0r = &xb[h][0][0];
    unsigned*       B0w = &xb[h][0][0];
    const unsigned* B1r = &xb[h][1][0];
    unsigned*       B1w = &xb[h][1][0];
#pragma unroll 1
    for (int it = 0; it < (NAPPS - 2) / 2; ++it) {   // apps 1..198
        run_app(B0r, B1w);
        run_app(B1r, B0w);
    }
    run_app(B0r, B1w);          // app 199
    run_app(B1r, nullptr);      // app 200: x final; w = window of app-199 state

    // ---- epilogue: out_row = r_a * sum_{gc<K} K[a][gc] c_gc ----
    unsigned cmask[NJ];
#pragma unroll
    for (int d = 0; d < NJ; ++d) {
        int g0 = gb + 2 * d, g1 = g0 + 1;
        h2 cw = uh(w[d]);
        float c0 = (g0 >= 0 && g0 < KTOP) ? (float)cw[0] : 0.f;
        float c1 = (g1 >= 0 && g1 < KTOP) ? (float)cw[1] : 0.f;
        cmask[d] = __builtin_bit_cast(unsigned, pack2(c0, c1));
    }
    float k0 = 0.f, k1 = 0.f;
#pragma unroll
    for (int d = 0; d < NJ; ++d) {
        k0 = __builtin_amdgcn_fdot2(K2[0][d], uh(cmask[d]), k0, false);
        k1 = __builtin_amdgcn_fdot2(K2[1][d], uh(cmask[d]), k1, false);
    }
    h2 xr = uh(x);
    out[b * N + ti[h][2 * t]]     = (float)xr[0] * k0;
    out[b * N + ti[h][2 * t + 1]] = (float)xr[1] * k1;
}

extern "C" void kernel_launch(void* const* d_in, const int* in_sizes, int n_in,
                              void* d_out, int out_size, void* d_ws, size_t ws_size,
                              hipStream_t stream) {
    const float* scores = (const float*)d_in[0];
    float* out = (float*)d_out;
    sinkhorn_topk_kernel<<<dim3(BATCH / 2), dim3(NT), 0, stream>>>(scores, out);
}